// Round 4
// baseline (302.726 us; speedup 1.0000x reference)
//
#include <hip/hip_runtime.h>
#include <hip/hip_bf16.h>
#include <hip/hip_fp16.h>
#include <stdint.h>

// ---------------------------------------------------------------------------
// AttentionLayer: Q=XWq+bq, K=XWk+bk, V=XWv+bv; O = softmax(QK^T) V
// B=4, N=2048, D=1024. fp32 I/O; internals fp16 (MFMA), S + accum fp32.
// R4: XOR-swizzled LDS chunk layout kills the 8-way ds_read_b128 bank
// conflicts (row-major [.][32] fp16 put all even rows in one bank quad).
// LDS[row][c] = global[row][c ^ swz(row)], swz(r) = (r&3)^((r>>2)&3).
// ---------------------------------------------------------------------------

typedef unsigned short ushort_t;
typedef __attribute__((ext_vector_type(8))) _Float16  f16x8;
typedef __attribute__((ext_vector_type(4))) _Float16  f16x4;
typedef __attribute__((ext_vector_type(4))) float     f32x4;

__device__ __forceinline__ void store_out(float* p, float v) { *p = v; }
__device__ __forceinline__ void store_out(__half* p, float v) { *p = __float2half(v); }

__device__ __forceinline__ void async_load16(const void* g, void* l) {
  __builtin_amdgcn_global_load_lds(
      (const __attribute__((address_space(1))) void*)g,
      (__attribute__((address_space(3))) void*)l, 16, 0, 0);
}

// ---------------------------------------------------------------------------
// Generic C[m][n] = sum_k A[m][k]*BT[n][k], fp16 in, fp32 acc. 128x128 tile,
// 2 BK=32 steps per barrier pair, swizzled LDS. K % 64 == 0.
// ---------------------------------------------------------------------------
template <typename OutT>
__global__ __launch_bounds__(256)
void gemm_bt_kernel(const ushort_t* __restrict__ A, const ushort_t* __restrict__ BT,
                    OutT* __restrict__ C, int N, int K,
                    long batchA, long batchB, long batchC)
{
  __shared__ ushort_t As[2][128 * 32];
  __shared__ ushort_t Bs[2][128 * 32];

  const int t    = threadIdx.x;
  const int lane = t & 63;
  const int wave = t >> 6;
  const int wm   = (wave >> 1) * 64;
  const int wn   = (wave & 1) * 64;

  const ushort_t* Ab = A + (long)blockIdx.z * batchA + (long)blockIdx.y * 128 * K;
  const ushort_t* Bb = BT + (long)blockIdx.z * batchB + (long)blockIdx.x * 128 * K;
  OutT* Cb = C + (long)blockIdx.z * batchC;

  // staging: lane t -> LDS slot (row=t>>2, chunk=t&3); load global chunk ^ swz
  const int ldr = t >> 2;
  const int swzs = (ldr & 3) ^ ((ldr >> 2) & 3);
  const int ldc = ((t & 3) ^ swzs) * 8;        // swizzled 16B col chunk
  // fragment read: global chunk (lane>>4), stored at chunk ^ swz(frow)
  const int frow = lane & 15;
  const int fsz  = (frow & 3) ^ ((frow >> 2) & 3);
  const int fo   = (((lane >> 4) ^ fsz)) * 8;

  f32x4 acc[4][4];
  const f32x4 zero = {0.0f, 0.0f, 0.0f, 0.0f};
#pragma unroll
  for (int i = 0; i < 4; ++i)
#pragma unroll
    for (int j = 0; j < 4; ++j) acc[i][j] = zero;

  for (int k0 = 0; k0 < K; k0 += 64) {
    __syncthreads();
    const ushort_t* ga = Ab + (long)ldr * K + k0 + ldc;
    const ushort_t* gb = Bb + (long)ldr * K + k0 + ldc;
#pragma unroll
    for (int h = 0; h < 2; ++h) {
      async_load16(ga + h * 32,                &As[h][t * 8]);
      async_load16(ga + h * 32 + 64 * (long)K, &As[h][2048 + t * 8]);
      async_load16(gb + h * 32,                &Bs[h][t * 8]);
      async_load16(gb + h * 32 + 64 * (long)K, &Bs[h][2048 + t * 8]);
    }
    __syncthreads();
#pragma unroll
    for (int h = 0; h < 2; ++h) {
      f16x8 af[4], bf[4];
#pragma unroll
      for (int i = 0; i < 4; ++i) {
        af[i] = *(const f16x8*)&As[h][(wm + i * 16 + frow) * 32 + fo];
        bf[i] = *(const f16x8*)&Bs[h][(wn + i * 16 + frow) * 32 + fo];
      }
#pragma unroll
      for (int mi = 0; mi < 4; ++mi)
#pragma unroll
        for (int ni = 0; ni < 4; ++ni)
          acc[mi][ni] = __builtin_amdgcn_mfma_f32_16x16x32_f16(af[mi], bf[ni], acc[mi][ni], 0, 0, 0);
    }
  }

  // C/D layout: col = lane&15, row = (lane>>4)*4 + reg
  const int er = (lane >> 4) * 4;
  const int ec = lane & 15;
#pragma unroll
  for (int ni = 0; ni < 4; ++ni) {
    const int gcol = blockIdx.x * 128 + wn + ni * 16 + ec;
#pragma unroll
    for (int mi = 0; mi < 4; ++mi) {
#pragma unroll
      for (int r = 0; r < 4; ++r) {
        const long grow = (long)blockIdx.y * 128 + wm + mi * 16 + er + r;
        store_out(&Cb[grow * (long)N + gcol], acc[mi][ni][r]);
      }
    }
  }
}

// ---------------------------------------------------------------------------
// Fused QKV projection: A = Xh [M][1024], BT = WtAll [3072][1024] (Wq|Wk|Wv).
// tgt = blockIdx.x>>3 selects Q / K / V-transposed output. Swizzled LDS.
// ---------------------------------------------------------------------------
__global__ __launch_bounds__(256)
void qkv_gemm_kernel(const ushort_t* __restrict__ A, const ushort_t* __restrict__ BT,
                     const float* __restrict__ bq, const float* __restrict__ bk,
                     const float* __restrict__ bvp,
                     __half* __restrict__ Qh, __half* __restrict__ Kh,
                     ushort_t* __restrict__ Vt)
{
  const int K = 1024;
  __shared__ ushort_t As[2][128 * 32];
  __shared__ ushort_t Bs[2][128 * 32];

  const int t    = threadIdx.x;
  const int lane = t & 63;
  const int wave = t >> 6;
  const int wm   = (wave >> 1) * 64;
  const int wn   = (wave & 1) * 64;

  const ushort_t* Ab = A + (long)blockIdx.y * 128 * K;
  const ushort_t* Bb = BT + (long)blockIdx.x * 128 * K;

  const int ldr = t >> 2;
  const int swzs = (ldr & 3) ^ ((ldr >> 2) & 3);
  const int ldc = ((t & 3) ^ swzs) * 8;
  const int frow = lane & 15;
  const int fsz  = (frow & 3) ^ ((frow >> 2) & 3);
  const int fo   = (((lane >> 4) ^ fsz)) * 8;

  f32x4 acc[4][4];
  const f32x4 zero = {0.0f, 0.0f, 0.0f, 0.0f};
#pragma unroll
  for (int i = 0; i < 4; ++i)
#pragma unroll
    for (int j = 0; j < 4; ++j) acc[i][j] = zero;

  for (int k0 = 0; k0 < K; k0 += 64) {
    __syncthreads();
    const ushort_t* ga = Ab + (long)ldr * K + k0 + ldc;
    const ushort_t* gb = Bb + (long)ldr * K + k0 + ldc;
#pragma unroll
    for (int h = 0; h < 2; ++h) {
      async_load16(ga + h * 32,                &As[h][t * 8]);
      async_load16(ga + h * 32 + 64 * (long)K, &As[h][2048 + t * 8]);
      async_load16(gb + h * 32,                &Bs[h][t * 8]);
      async_load16(gb + h * 32 + 64 * (long)K, &Bs[h][2048 + t * 8]);
    }
    __syncthreads();
#pragma unroll
    for (int h = 0; h < 2; ++h) {
      f16x8 af[4], bf[4];
#pragma unroll
      for (int i = 0; i < 4; ++i) {
        af[i] = *(const f16x8*)&As[h][(wm + i * 16 + frow) * 32 + fo];
        bf[i] = *(const f16x8*)&Bs[h][(wn + i * 16 + frow) * 32 + fo];
      }
#pragma unroll
      for (int mi = 0; mi < 4; ++mi)
#pragma unroll
        for (int ni = 0; ni < 4; ++ni)
          acc[mi][ni] = __builtin_amdgcn_mfma_f32_16x16x32_f16(af[mi], bf[ni], acc[mi][ni], 0, 0, 0);
    }
  }

  const int er = (lane >> 4) * 4;
  const int ec = lane & 15;
  const int tgt = blockIdx.x >> 3;  // 0:Q 1:K 2:V (block-uniform)
  const float* bias = (tgt == 0) ? bq : (tgt == 1) ? bk : bvp;
#pragma unroll
  for (int ni = 0; ni < 4; ++ni) {
    const int c = (blockIdx.x & 7) * 128 + wn + ni * 16 + ec;  // 0..1023
    const float bval = bias[c];
#pragma unroll
    for (int mi = 0; mi < 4; ++mi) {
      const long grow0 = (long)blockIdx.y * 128 + wm + mi * 16 + er;
      if (tgt < 2) {
        __half* o = (tgt == 0) ? Qh : Kh;
#pragma unroll
        for (int r = 0; r < 4; ++r)
          o[(grow0 + r) * 1024 + c] = __float2half(acc[mi][ni][r] + bval);
      } else {
        const long b  = grow0 >> 11;       // batch (N=2048 rows per batch)
        const long ml = grow0 & 2047;      // aligned to 4
        f16x4 v4;
#pragma unroll
        for (int r = 0; r < 4; ++r) v4[r] = (_Float16)(acc[mi][ni][r] + bval);
        *(f16x4*)&Vt[b * 2097152 + (long)c * 2048 + ml] = v4;  // 8B store
      }
    }
  }
}

// ---------------------------------------------------------------------------
// fp32 -> fp16 elementwise, 8 elems/thread, 16B stores.
// ---------------------------------------------------------------------------
__global__ __launch_bounds__(256)
void cvt_f32_f16_kernel(const float* __restrict__ src, __half* __restrict__ dst, long n)
{
  const long i = ((long)blockIdx.x * 256 + threadIdx.x) * 8;
  if (i + 8 > n) return;
  const float4 a = *(const float4*)(src + i);
  const float4 b = *(const float4*)(src + i + 4);
  f16x8 h;
  h[0] = (_Float16)a.x; h[1] = (_Float16)a.y; h[2] = (_Float16)a.z; h[3] = (_Float16)a.w;
  h[4] = (_Float16)b.x; h[5] = (_Float16)b.y; h[6] = (_Float16)b.z; h[7] = (_Float16)b.w;
  *(f16x8*)((ushort_t*)dst + i) = h;
}

// ---------------------------------------------------------------------------
// Batched weight transpose+convert: dst[z][c][r] = (fp16)srcz[r][c], 1024x1024.
// ---------------------------------------------------------------------------
__global__ __launch_bounds__(256)
void transpose_cvt3_kernel(const float* __restrict__ W0, const float* __restrict__ W1,
                           const float* __restrict__ W2, __half* __restrict__ dst)
{
  __shared__ float tile[32][33];
  const int z = blockIdx.z;
  const float* src = (z == 0) ? W0 : (z == 1) ? W1 : W2;
  __half* d = dst + (long)z * 1024 * 1024;
  const int c0 = blockIdx.x * 32;
  const int r0 = blockIdx.y * 32;
  const int tx = threadIdx.x & 31;
  const int ty = threadIdx.x >> 5;
#pragma unroll
  for (int i = 0; i < 32; i += 8)
    tile[ty + i][tx] = src[(long)(r0 + ty + i) * 1024 + (c0 + tx)];
  __syncthreads();
#pragma unroll
  for (int i = 0; i < 32; i += 8)
    d[(long)(c0 + ty + i) * 1024 + (r0 + tx)] = __float2half(tile[tx][ty + i]);
}

// ---------------------------------------------------------------------------
// Row softmax over 2048 fp32 cols -> fp16. One 256-thread block per row.
// ---------------------------------------------------------------------------
__global__ __launch_bounds__(256)
void softmax2048_kernel(const float* __restrict__ S, __half* __restrict__ P)
{
  const long row = blockIdx.x;
  const float* s = S + row * 2048;
  const int t = threadIdx.x;

  const float4 a = ((const float4*)s)[t * 2];
  const float4 b = ((const float4*)s)[t * 2 + 1];
  float v[8] = {a.x, a.y, a.z, a.w, b.x, b.y, b.z, b.w};

  float mx = v[0];
#pragma unroll
  for (int i = 1; i < 8; ++i) mx = fmaxf(mx, v[i]);
#pragma unroll
  for (int off = 32; off > 0; off >>= 1) mx = fmaxf(mx, __shfl_xor(mx, off, 64));

  __shared__ float redm[4], reds[4];
  if ((t & 63) == 0) redm[t >> 6] = mx;
  __syncthreads();
  mx = fmaxf(fmaxf(redm[0], redm[1]), fmaxf(redm[2], redm[3]));

  float sum = 0.0f;
#pragma unroll
  for (int i = 0; i < 8; ++i) { v[i] = __expf(v[i] - mx); sum += v[i]; }
#pragma unroll
  for (int off = 32; off > 0; off >>= 1) sum += __shfl_xor(sum, off, 64);
  if ((t & 63) == 0) reds[t >> 6] = sum;
  __syncthreads();
  sum = reds[0] + reds[1] + reds[2] + reds[3];

  const float inv = 1.0f / sum;
  f16x8 h;
#pragma unroll
  for (int i = 0; i < 8; ++i) h[i] = (_Float16)(v[i] * inv);
  *(f16x8*)((ushort_t*)P + row * 2048 + t * 8) = h;
}

// ---------------------------------------------------------------------------
extern "C" void kernel_launch(void* const* d_in, const int* in_sizes, int n_in,
                              void* d_out, int out_size, void* d_ws, size_t ws_size,
                              hipStream_t stream)
{
  const int  Bb = 4, Nn = 2048, Dd = 1024;
  const long BN = (long)Bb * Nn;  // 8192

  const float* X  = (const float*)d_in[0];
  const float* Wq = (const float*)d_in[1];
  const float* bq = (const float*)d_in[2];
  const float* Wk = (const float*)d_in[3];
  const float* bk = (const float*)d_in[4];
  const float* Wv = (const float*)d_in[5];
  const float* bv = (const float*)d_in[6];
  float* Out      = (float*)d_out;

  uint8_t* w = (uint8_t*)d_ws;
  ushort_t* Wt = (ushort_t*)w;  w += (size_t)3 * Dd * Dd * 2;  // Wq^T|Wk^T|Wv^T fp16

  // Wt[z][e][k] = W[k][e], fp32 -> fp16
  transpose_cvt3_kernel<<<dim3(Dd / 32, Dd / 32, 3), 256, 0, stream>>>(Wq, Wk, Wv, (__half*)Wt);

  const size_t fullNeed = (size_t)3 * Dd * Dd * 2      // Wt
                        + 4 * ((size_t)BN * Dd * 2)    // Xh, Q, K, Vt fp16
                        + (size_t)Bb * Nn * Nn * 4     // S fp32
                        + (size_t)Bb * Nn * Nn * 2;    // P fp16

  if (ws_size >= fullNeed) {
    ushort_t* Xh = (ushort_t*)w;  w += (size_t)BN * Dd * 2;
    ushort_t* Q  = (ushort_t*)w;  w += (size_t)BN * Dd * 2;
    ushort_t* Kb = (ushort_t*)w;  w += (size_t)BN * Dd * 2;
    ushort_t* Vt = (ushort_t*)w;  w += (size_t)BN * Dd * 2;  // [B][Dd][Nn]
    float*    S  = (float*)w;     w += (size_t)Bb * Nn * Nn * 4;
    ushort_t* P  = (ushort_t*)w;

    // X -> fp16
    cvt_f32_f16_kernel<<<dim3((unsigned)(BN * Dd / (8 * 256))), 256, 0, stream>>>(
        X, (__half*)Xh, BN * Dd);

    // Fused QKV: [8192,1024] x [3072,1024]^T (+bias); V written transposed
    qkv_gemm_kernel<<<dim3(3 * Dd / 128, BN / 128, 1), 256, 0, stream>>>(
        Xh, Wt, bq, bk, bv, (__half*)Q, (__half*)Kb, Vt);

    // S[b] = Q[b] K[b]^T  (fp32)
    gemm_bt_kernel<float><<<dim3(Nn / 128, Nn / 128, Bb), 256, 0, stream>>>(
        Q, Kb, S, Nn, Dd, (long)Nn * Dd, (long)Nn * Dd, (long)Nn * Nn);

    // P = softmax(S) rows -> fp16
    softmax2048_kernel<<<dim3((unsigned)(Bb * (long)Nn)), 256, 0, stream>>>(S, (__half*)P);

    // O[b] = P[b] V[b] via Vt -> fp32 out
    gemm_bt_kernel<float><<<dim3(Dd / 128, Nn / 128, Bb), 256, 0, stream>>>(
        P, Vt, Out, Dd, Nn, (long)Nn * Nn, (long)Dd * Nn, (long)Nn * Dd);
  } else {
    // Per-batch fallback (~48 MB ws)
    ushort_t* Xh = (ushort_t*)w;  w += (size_t)Nn * Dd * 2;
    ushort_t* Q  = (ushort_t*)w;  w += (size_t)Nn * Dd * 2;
    ushort_t* Kb = (ushort_t*)w;  w += (size_t)Nn * Dd * 2;
    ushort_t* Vt = (ushort_t*)w;  w += (size_t)Nn * Dd * 2;
    float*    S  = (float*)w;     w += (size_t)Nn * Nn * 4;
    ushort_t* P  = (ushort_t*)w;

    for (int b = 0; b < Bb; ++b) {
      const float* Xb = X + (long)b * Nn * Dd;
      cvt_f32_f16_kernel<<<dim3((unsigned)((long)Nn * Dd / (8 * 256))), 256, 0, stream>>>(
          Xb, (__half*)Xh, (long)Nn * Dd);
      qkv_gemm_kernel<<<dim3(3 * Dd / 128, Nn / 128, 1), 256, 0, stream>>>(
          Xh, Wt, bq, bk, bv, (__half*)Q, (__half*)Kb, Vt);
      gemm_bt_kernel<float><<<dim3(Nn / 128, Nn / 128, 1), 256, 0, stream>>>(
          Q, Kb, S, Nn, Dd, 0, 0, 0);
      softmax2048_kernel<<<dim3(Nn), 256, 0, stream>>>(S, (__half*)P);
      gemm_bt_kernel<float><<<dim3(Dd / 128, Nn / 128, 1), 256, 0, stream>>>(
          P, Vt, Out + (long)b * Nn * Dd, Dd, Nn, 0, 0, 0);
    }
  }
}

// Round 6
// 273.585 us; speedup vs baseline: 1.1065x; 1.1065x over previous
//
#include <hip/hip_runtime.h>
#include <hip/hip_bf16.h>
#include <hip/hip_fp16.h>
#include <stdint.h>
#include <math.h>

// ---------------------------------------------------------------------------
// AttentionLayer: Q=XWq+bq, K=XWk+bk, V=XWv+bv; O = softmax(QK^T) V
// B=4, N=2048, D=1024. fp32 I/O; internals fp16, accumulation fp32.
// R6: softmax fused into GEMM pair, 64-col stat granularity (one wave-half):
// each wave writes its own per-row partial max/expsum (no cross-half combine
// -- R5's bug was mixing 64-col p_unnorm with 128-col stats). Reduce kernel
// folds 32 partials into per-(row,chunk) scales; PV applies them post-LDS.
// ---------------------------------------------------------------------------

typedef unsigned short ushort_t;
typedef __attribute__((ext_vector_type(8))) _Float16  f16x8;
typedef __attribute__((ext_vector_type(4))) _Float16  f16x4;
typedef __attribute__((ext_vector_type(4))) float     f32x4;

__device__ __forceinline__ void async_load16(const void* g, void* l) {
  __builtin_amdgcn_global_load_lds(
      (const __attribute__((address_space(1))) void*)g,
      (__attribute__((address_space(3))) void*)l, 16, 0, 0);
}

// ---------------------------------------------------------------------------
// Fused QKV projection: A = Xh [8192][1024], BT = Wt [3072][1024] (Wq|Wk|Wv).
// tgt = blockIdx.x>>3 selects Q / K / V-transposed output. Swizzled LDS.
// ---------------------------------------------------------------------------
__global__ __launch_bounds__(256)
void qkv_gemm_kernel(const ushort_t* __restrict__ A, const ushort_t* __restrict__ BT,
                     const float* __restrict__ bq, const float* __restrict__ bk,
                     const float* __restrict__ bvp,
                     __half* __restrict__ Qh, __half* __restrict__ Kh,
                     ushort_t* __restrict__ Vt)
{
  const int K = 1024;
  __shared__ ushort_t As[2][128 * 32];
  __shared__ ushort_t Bs[2][128 * 32];

  const int t    = threadIdx.x;
  const int lane = t & 63;
  const int wave = t >> 6;
  const int wm   = (wave >> 1) * 64;
  const int wn   = (wave & 1) * 64;

  const ushort_t* Ab = A + (long)blockIdx.y * 128 * K;
  const ushort_t* Bb = BT + (long)blockIdx.x * 128 * K;

  const int ldr = t >> 2;
  const int swzs = (ldr & 3) ^ ((ldr >> 2) & 3);
  const int ldc = ((t & 3) ^ swzs) * 8;
  const int frow = lane & 15;
  const int fsz  = (frow & 3) ^ ((frow >> 2) & 3);
  const int fo   = (((lane >> 4) ^ fsz)) * 8;

  f32x4 acc[4][4];
  const f32x4 zero = {0.0f, 0.0f, 0.0f, 0.0f};
#pragma unroll
  for (int i = 0; i < 4; ++i)
#pragma unroll
    for (int j = 0; j < 4; ++j) acc[i][j] = zero;

  for (int k0 = 0; k0 < K; k0 += 64) {
    __syncthreads();
    const ushort_t* ga = Ab + (long)ldr * K + k0 + ldc;
    const ushort_t* gb = Bb + (long)ldr * K + k0 + ldc;
#pragma unroll
    for (int h = 0; h < 2; ++h) {
      async_load16(ga + h * 32,                &As[h][t * 8]);
      async_load16(ga + h * 32 + 64 * (long)K, &As[h][2048 + t * 8]);
      async_load16(gb + h * 32,                &Bs[h][t * 8]);
      async_load16(gb + h * 32 + 64 * (long)K, &Bs[h][2048 + t * 8]);
    }
    __syncthreads();
#pragma unroll
    for (int h = 0; h < 2; ++h) {
      f16x8 af[4], bf[4];
#pragma unroll
      for (int i = 0; i < 4; ++i) {
        af[i] = *(const f16x8*)&As[h][(wm + i * 16 + frow) * 32 + fo];
        bf[i] = *(const f16x8*)&Bs[h][(wn + i * 16 + frow) * 32 + fo];
      }
#pragma unroll
      for (int mi = 0; mi < 4; ++mi)
#pragma unroll
        for (int ni = 0; ni < 4; ++ni)
          acc[mi][ni] = __builtin_amdgcn_mfma_f32_16x16x32_f16(af[mi], bf[ni], acc[mi][ni], 0, 0, 0);
    }
  }

  const int er = (lane >> 4) * 4;
  const int ec = lane & 15;
  const int tgt = blockIdx.x >> 3;  // 0:Q 1:K 2:V (block-uniform)
  const float* bias = (tgt == 0) ? bq : (tgt == 1) ? bk : bvp;
#pragma unroll
  for (int ni = 0; ni < 4; ++ni) {
    const int c = (blockIdx.x & 7) * 128 + wn + ni * 16 + ec;  // 0..1023
    const float bval = bias[c];
#pragma unroll
    for (int mi = 0; mi < 4; ++mi) {
      const long grow0 = (long)blockIdx.y * 128 + wm + mi * 16 + er;
      if (tgt < 2) {
        __half* o = (tgt == 0) ? Qh : Kh;
#pragma unroll
        for (int r = 0; r < 4; ++r)
          o[(grow0 + r) * 1024 + c] = __float2half(acc[mi][ni][r] + bval);
      } else {
        const long b  = grow0 >> 11;       // batch (2048 rows per batch)
        const long ml = grow0 & 2047;      // aligned to 4
        f16x4 v4;
#pragma unroll
        for (int r = 0; r < 4; ++r) v4[r] = (_Float16)(acc[mi][ni][r] + bval);
        *(f16x4*)&Vt[b * 2097152 + (long)c * 2048 + ml] = v4;  // 8B store
      }
    }
  }
}

// ---------------------------------------------------------------------------
// QK^T with fused partial softmax, 64-col chunk granularity. Per batch z:
// S[row][col] = exp(s - m_chunk) fp16; PM/PS[z][32][2048] per-chunk row
// max & expsum, written straight from the owning wave (chunk == wave-half).
// Grid (16,16,4). K=1024.
// ---------------------------------------------------------------------------
__global__ __launch_bounds__(256)
void qk_gemm_kernel(const ushort_t* __restrict__ Q, const ushort_t* __restrict__ Kh,
                    __half* __restrict__ S, float* __restrict__ PM, float* __restrict__ PS)
{
  const int K = 1024;
  __shared__ ushort_t As[2][128 * 32];
  __shared__ ushort_t Bs[2][128 * 32];

  const int t    = threadIdx.x;
  const int lane = t & 63;
  const int wave = t >> 6;
  const int wm   = (wave >> 1) * 64;
  const int wn   = (wave & 1) * 64;
  const long z   = blockIdx.z;

  const ushort_t* Ab = Q + z * 2048 * 1024 + (long)blockIdx.y * 128 * K;
  const ushort_t* Bb = Kh + z * 2048 * 1024 + (long)blockIdx.x * 128 * K;
  __half* Sb = S + z * 2048 * 2048;

  const int ldr = t >> 2;
  const int swzs = (ldr & 3) ^ ((ldr >> 2) & 3);
  const int ldc = ((t & 3) ^ swzs) * 8;
  const int frow = lane & 15;
  const int fsz  = (frow & 3) ^ ((frow >> 2) & 3);
  const int fo   = (((lane >> 4) ^ fsz)) * 8;

  f32x4 acc[4][4];
  const f32x4 zero = {0.0f, 0.0f, 0.0f, 0.0f};
#pragma unroll
  for (int i = 0; i < 4; ++i)
#pragma unroll
    for (int j = 0; j < 4; ++j) acc[i][j] = zero;

  for (int k0 = 0; k0 < K; k0 += 64) {
    __syncthreads();
    const ushort_t* ga = Ab + (long)ldr * K + k0 + ldc;
    const ushort_t* gb = Bb + (long)ldr * K + k0 + ldc;
#pragma unroll
    for (int h = 0; h < 2; ++h) {
      async_load16(ga + h * 32,                &As[h][t * 8]);
      async_load16(ga + h * 32 + 64 * (long)K, &As[h][2048 + t * 8]);
      async_load16(gb + h * 32,                &Bs[h][t * 8]);
      async_load16(gb + h * 32 + 64 * (long)K, &Bs[h][2048 + t * 8]);
    }
    __syncthreads();
#pragma unroll
    for (int h = 0; h < 2; ++h) {
      f16x8 af[4], bf[4];
#pragma unroll
      for (int i = 0; i < 4; ++i) {
        af[i] = *(const f16x8*)&As[h][(wm + i * 16 + frow) * 32 + fo];
        bf[i] = *(const f16x8*)&Bs[h][(wn + i * 16 + frow) * 32 + fo];
      }
#pragma unroll
      for (int mi = 0; mi < 4; ++mi)
#pragma unroll
        for (int ni = 0; ni < 4; ++ni)
          acc[mi][ni] = __builtin_amdgcn_mfma_f32_16x16x32_f16(af[mi], bf[ni], acc[mi][ni], 0, 0, 0);
    }
  }

  // Epilogue. C/D layout: row_local = wm+mi*16+er+r, col_local = wn+ni*16+ec.
  // This wave owns 64-col chunk cc; its row max/expsum ARE the chunk stats.
  const int er = (lane >> 4) * 4;
  const int ec = lane & 15;
  const int cc = blockIdx.x * 2 + (wave & 1);   // 0..31
  float* PMb = PM + z * 32 * 2048 + (long)cc * 2048;
  float* PSb = PS + z * 32 * 2048 + (long)cc * 2048;

#pragma unroll
  for (int mi = 0; mi < 4; ++mi)
#pragma unroll
    for (int r = 0; r < 4; ++r) {
      float m = fmaxf(fmaxf(acc[mi][0][r], acc[mi][1][r]),
                      fmaxf(acc[mi][2][r], acc[mi][3][r]));
      m = fmaxf(m, __shfl_xor(m, 1));   // reduce over the 16 ec lanes
      m = fmaxf(m, __shfl_xor(m, 2));
      m = fmaxf(m, __shfl_xor(m, 4));
      m = fmaxf(m, __shfl_xor(m, 8));
      float s = 0.0f;
#pragma unroll
      for (int ni = 0; ni < 4; ++ni) {
        const float e = __expf(acc[mi][ni][r] - m);
        acc[mi][ni][r] = e;
        s += e;
      }
      s += __shfl_xor(s, 1);
      s += __shfl_xor(s, 2);
      s += __shfl_xor(s, 4);
      s += __shfl_xor(s, 8);
      if (ec == 0) {
        const long row = (long)blockIdx.y * 128 + wm + mi * 16 + er + r;
        PMb[row] = m;
        PSb[row] = s;
      }
    }

  // store p_unnorm = exp(s - m_chunk) fp16
#pragma unroll
  for (int ni = 0; ni < 4; ++ni) {
    const long col = (long)blockIdx.x * 128 + wn + ni * 16 + ec;
#pragma unroll
    for (int mi = 0; mi < 4; ++mi)
#pragma unroll
      for (int r = 0; r < 4; ++r) {
        const long grow = (long)blockIdx.y * 128 + wm + mi * 16 + er + r;
        Sb[grow * 2048 + col] = __float2half(acc[mi][ni][r]);
      }
  }
}

// ---------------------------------------------------------------------------
// Fold 32 chunk partials into per-(row,chunk) scale = exp(pm-m)/l.
// One thread per (batch,row); 8192 threads.
// ---------------------------------------------------------------------------
__global__ __launch_bounds__(256)
void softmax_reduce_kernel(const float* __restrict__ PM, const float* __restrict__ PS,
                           float* __restrict__ Sc)
{
  const int r = blockIdx.x * 256 + threadIdx.x;   // 0..8191
  const int b = r >> 11, row = r & 2047;
  const long base = (long)b * 32 * 2048 + row;
  float m = -3.4e38f;
#pragma unroll
  for (int cb = 0; cb < 32; ++cb) m = fmaxf(m, PM[base + cb * 2048]);
  float l = 0.0f;
#pragma unroll
  for (int cb = 0; cb < 32; ++cb) l += PS[base + cb * 2048] * __expf(PM[base + cb * 2048] - m);
  const float inv = 1.0f / l;
#pragma unroll
  for (int cb = 0; cb < 32; ++cb) Sc[base + cb * 2048] = __expf(PM[base + cb * 2048] - m) * inv;
}

// ---------------------------------------------------------------------------
// PV: Out[m][e] = sum_k (S[m][k]*scale[m][k>>6]) * Vt[e][k]. Scale applied to
// A-fragments post-LDS-read (row = m, chunk = k0>>6). Grid (8,16,4), K=2048.
// ---------------------------------------------------------------------------
__global__ __launch_bounds__(256)
void pv_gemm_kernel(const ushort_t* __restrict__ S, const ushort_t* __restrict__ Vt,
                    const float* __restrict__ Sc, float* __restrict__ Out)
{
  const int K = 2048;
  __shared__ ushort_t As[2][128 * 32];
  __shared__ ushort_t Bs[2][128 * 32];

  const int t    = threadIdx.x;
  const int lane = t & 63;
  const int wave = t >> 6;
  const int wm   = (wave >> 1) * 64;
  const int wn   = (wave & 1) * 64;
  const long z   = blockIdx.z;

  const ushort_t* Ab = S + z * 2048 * 2048 + (long)blockIdx.y * 128 * K;
  const ushort_t* Bb = Vt + z * 1024 * 2048 + (long)blockIdx.x * 128 * K;
  const float* Scb = Sc + z * 32 * 2048;
  float* Cb = Out + z * 2048 * 1024;

  const int ldr = t >> 2;
  const int swzs = (ldr & 3) ^ ((ldr >> 2) & 3);
  const int ldc = ((t & 3) ^ swzs) * 8;
  const int frow = lane & 15;
  const int fsz  = (frow & 3) ^ ((frow >> 2) & 3);
  const int fo   = (((lane >> 4) ^ fsz)) * 8;

  const int arow0 = blockIdx.y * 128 + wm + frow;  // this lane's A rows: +i*16

  f32x4 acc[4][4];
  const f32x4 zero = {0.0f, 0.0f, 0.0f, 0.0f};
#pragma unroll
  for (int i = 0; i < 4; ++i)
#pragma unroll
    for (int j = 0; j < 4; ++j) acc[i][j] = zero;

  for (int k0 = 0; k0 < K; k0 += 64) {
    const int cb = k0 >> 6;   // 64-col stat chunk, one per iteration
    _Float16 sc16[4];
#pragma unroll
    for (int i = 0; i < 4; ++i)
      sc16[i] = (_Float16)Scb[(long)cb * 2048 + arow0 + i * 16];

    __syncthreads();
    const ushort_t* ga = Ab + (long)ldr * K + k0 + ldc;
    const ushort_t* gb = Bb + (long)ldr * K + k0 + ldc;
#pragma unroll
    for (int h = 0; h < 2; ++h) {
      async_load16(ga + h * 32,                &As[h][t * 8]);
      async_load16(ga + h * 32 + 64 * (long)K, &As[h][2048 + t * 8]);
      async_load16(gb + h * 32,                &Bs[h][t * 8]);
      async_load16(gb + h * 32 + 64 * (long)K, &Bs[h][2048 + t * 8]);
    }
    __syncthreads();
#pragma unroll
    for (int h = 0; h < 2; ++h) {
      f16x8 af[4], bf[4];
#pragma unroll
      for (int i = 0; i < 4; ++i) {
        af[i] = *(const f16x8*)&As[h][(wm + i * 16 + frow) * 32 + fo] * sc16[i];
        bf[i] = *(const f16x8*)&Bs[h][(wn + i * 16 + frow) * 32 + fo];
      }
#pragma unroll
      for (int mi = 0; mi < 4; ++mi)
#pragma unroll
        for (int ni = 0; ni < 4; ++ni)
          acc[mi][ni] = __builtin_amdgcn_mfma_f32_16x16x32_f16(af[mi], bf[ni], acc[mi][ni], 0, 0, 0);
    }
  }

  const int er = (lane >> 4) * 4;
  const int ec = lane & 15;
#pragma unroll
  for (int ni = 0; ni < 4; ++ni) {
    const int gcol = blockIdx.x * 128 + wn + ni * 16 + ec;
#pragma unroll
    for (int mi = 0; mi < 4; ++mi) {
#pragma unroll
      for (int r = 0; r < 4; ++r) {
        const long grow = (long)blockIdx.y * 128 + wm + mi * 16 + er + r;
        Cb[grow * 1024 + gcol] = acc[mi][ni][r];
      }
    }
  }
}

// ---------------------------------------------------------------------------
// fp32 -> fp16 elementwise, 8 elems/thread, 16B stores.
// ---------------------------------------------------------------------------
__global__ __launch_bounds__(256)
void cvt_f32_f16_kernel(const float* __restrict__ src, __half* __restrict__ dst, long n)
{
  const long i = ((long)blockIdx.x * 256 + threadIdx.x) * 8;
  if (i + 8 > n) return;
  const float4 a = *(const float4*)(src + i);
  const float4 b = *(const float4*)(src + i + 4);
  f16x8 h;
  h[0] = (_Float16)a.x; h[1] = (_Float16)a.y; h[2] = (_Float16)a.z; h[3] = (_Float16)a.w;
  h[4] = (_Float16)b.x; h[5] = (_Float16)b.y; h[6] = (_Float16)b.z; h[7] = (_Float16)b.w;
  *(f16x8*)((ushort_t*)dst + i) = h;
}

// ---------------------------------------------------------------------------
// Batched weight transpose+convert: dst[z][c][r] = (fp16)srcz[r][c], 1024x1024.
// ---------------------------------------------------------------------------
__global__ __launch_bounds__(256)
void transpose_cvt3_kernel(const float* __restrict__ W0, const float* __restrict__ W1,
                           const float* __restrict__ W2, __half* __restrict__ dst)
{
  __shared__ float tile[32][33];
  const int z = blockIdx.z;
  const float* src = (z == 0) ? W0 : (z == 1) ? W1 : W2;
  __half* d = dst + (long)z * 1024 * 1024;
  const int c0 = blockIdx.x * 32;
  const int r0 = blockIdx.y * 32;
  const int tx = threadIdx.x & 31;
  const int ty = threadIdx.x >> 5;
#pragma unroll
  for (int i = 0; i < 32; i += 8)
    tile[ty + i][tx] = src[(long)(r0 + ty + i) * 1024 + (c0 + tx)];
  __syncthreads();
#pragma unroll
  for (int i = 0; i < 32; i += 8)
    d[(long)(c0 + ty + i) * 1024 + (r0 + tx)] = __float2half(tile[tx][ty + i]);
}

// ---------------------------------------------------------------------------
extern "C" void kernel_launch(void* const* d_in, const int* in_sizes, int n_in,
                              void* d_out, int out_size, void* d_ws, size_t ws_size,
                              hipStream_t stream)
{
  const int  Bb = 4, Nn = 2048, Dd = 1024;
  const long BN = (long)Bb * Nn;  // 8192

  const float* X  = (const float*)d_in[0];
  const float* Wq = (const float*)d_in[1];
  const float* bq = (const float*)d_in[2];
  const float* Wk = (const float*)d_in[3];
  const float* bk = (const float*)d_in[4];
  const float* Wv = (const float*)d_in[5];
  const float* bv = (const float*)d_in[6];
  float* Out      = (float*)d_out;

  uint8_t* w = (uint8_t*)d_ws;
  ushort_t* Wt = (ushort_t*)w;  w += (size_t)3 * Dd * Dd * 2;  // Wq^T|Wk^T|Wv^T fp16

  transpose_cvt3_kernel<<<dim3(Dd / 32, Dd / 32, 3), 256, 0, stream>>>(Wq, Wk, Wv, (__half*)Wt);

  const size_t statsBytes = (size_t)Bb * 32 * Nn * 4;   // 1 MB each
  const size_t fullNeed = (size_t)3 * Dd * Dd * 2       // Wt
                        + 4 * ((size_t)BN * Dd * 2)     // Xh, Q, K, Vt fp16
                        + (size_t)Bb * Nn * Nn * 2      // S fp16
                        + 3 * statsBytes;               // PM, PS, Sc

  if (ws_size >= fullNeed) {
    ushort_t* Xh = (ushort_t*)w;  w += (size_t)BN * Dd * 2;
    ushort_t* Q  = (ushort_t*)w;  w += (size_t)BN * Dd * 2;
    ushort_t* Kb = (ushort_t*)w;  w += (size_t)BN * Dd * 2;
    ushort_t* Vt = (ushort_t*)w;  w += (size_t)BN * Dd * 2;  // [B][Dd][Nn]
    ushort_t* S  = (ushort_t*)w;  w += (size_t)Bb * Nn * Nn * 2;
    float*    PM = (float*)w;     w += statsBytes;
    float*    PS = (float*)w;     w += statsBytes;
    float*    Sc = (float*)w;

    cvt_f32_f16_kernel<<<dim3((unsigned)(BN * Dd / (8 * 256))), 256, 0, stream>>>(
        X, (__half*)Xh, BN * Dd);

    qkv_gemm_kernel<<<dim3(3 * Dd / 128, BN / 128, 1), 256, 0, stream>>>(
        Xh, Wt, bq, bk, bv, (__half*)Q, (__half*)Kb, Vt);

    qk_gemm_kernel<<<dim3(Nn / 128, Nn / 128, Bb), 256, 0, stream>>>(
        Q, Kb, (__half*)S, PM, PS);

    softmax_reduce_kernel<<<dim3((unsigned)(Bb * Nn / 256)), 256, 0, stream>>>(PM, PS, Sc);

    pv_gemm_kernel<<<dim3(Dd / 128, Nn / 128, Bb), 256, 0, stream>>>(
        S, Vt, Sc, Out);
  } else {
    // Per-batch fallback (~32 MB ws): same kernels, z-extent 1
    ushort_t* Xh = (ushort_t*)w;  w += (size_t)Nn * Dd * 2;
    ushort_t* Q  = (ushort_t*)w;  w += (size_t)Nn * Dd * 2;
    ushort_t* Kb = (ushort_t*)w;  w += (size_t)Nn * Dd * 2;
    ushort_t* Vt = (ushort_t*)w;  w += (size_t)Nn * Dd * 2;
    ushort_t* S  = (ushort_t*)w;  w += (size_t)Nn * Nn * 2;
    float*    PM = (float*)w;     w += (size_t)32 * Nn * 4;
    float*    PS = (float*)w;     w += (size_t)32 * Nn * 4;
    float*    Sc = (float*)w;

    for (int b = 0; b < Bb; ++b) {
      const float* Xb = X + (long)b * Nn * Dd;
      cvt_f32_f16_kernel<<<dim3((unsigned)((long)Nn * Dd / (8 * 256))), 256, 0, stream>>>(
          Xb, (__half*)Xh, (long)Nn * Dd);
      qkv_gemm_kernel<<<dim3(3 * Dd / 128, Nn / 128, 1), 256, 0, stream>>>(
          Xh, Wt, bq, bk, bv, (__half*)Q, (__half*)Kb, Vt);
      qk_gemm_kernel<<<dim3(Nn / 128, Nn / 128, 1), 256, 0, stream>>>(
          Q, Kb, (__half*)S, PM, PS);
      softmax_reduce_kernel<<<dim3((unsigned)(Nn / 256)), 256, 0, stream>>>(PM, PS, Sc);
      pv_gemm_kernel<<<dim3(Dd / 128, Nn / 128, 1), 256, 0, stream>>>(
          S, Vt, Sc, Out + (long)b * Nn * Dd);
    }
  }
}